// Round 8
// baseline (145.343 us; speedup 1.0000x reference)
//
#include <hip/hip_runtime.h>
#include <math.h>

#define NODES   16384
#define NGRAPH  1024
#define EDGES   245760
#define EPG     240
#define FDIM    256

#define OUT_MEAN  0
#define OUT_STD   24576
#define OUT_SCANS 49152
#define OUT_RECON 376832

typedef __attribute__((ext_vector_type(4))) short bf16x4;
typedef __attribute__((ext_vector_type(8))) short bf16x8;
typedef __attribute__((ext_vector_type(4))) float f32x4;

static __device__ __forceinline__ float lrelu02(float v){ return v > 0.f ? v : 0.2f*v; }

static __device__ __forceinline__ unsigned short f2bf(float f){
    unsigned u = __float_as_uint(f);
    u = (u + 0x7FFFu + ((u >> 16) & 1u)) >> 16;
    return (unsigned short)u;
}

// ============ prep kernel: wtrans + fc1 transpose + ea partials + lidar =====
// blocks 0..511   : WT2/WT3 transpose+bf16
// blocks 512..639 : fc1WT bf16 (128 rows x 512 cols)
// blocks 640..895 : ea partial sums (960 edges each)
// blocks 896..2943: lidar (8 nodes per block, 32 lanes per node)
__global__ __launch_bounds__(256) void prep_kernel(
    const float* __restrict__ x,  const float* __restrict__ ea,
    const float* __restrict__ W2, const float* __restrict__ W3,
    const float* __restrict__ F1,
    const float* __restrict__ w1, const float* __restrict__ b1,
    const float* __restrict__ w2, const float* __restrict__ b2,
    const float* __restrict__ wl, const float* __restrict__ bl,
    const float* __restrict__ dw1, const float* __restrict__ db1,
    const float* __restrict__ dw2, const float* __restrict__ db2,
    unsigned short* __restrict__ T2, unsigned short* __restrict__ T3,
    unsigned short* __restrict__ T1, float* __restrict__ partial,
    float* __restrict__ out)
{
    __shared__ float red[256];
    __shared__ float sc[8][25];
    __shared__ float pooled[8][160];
    __shared__ float hid_lds[8][32];

    const int b = blockIdx.x;
    const int tid = threadIdx.x;

    if (b < 512) {
        const float* W = (b < 256) ? W2 : W3;
        unsigned short* T = (b < 256) ? T2 : T3;
        const int n = b & 255;
        T[n * 256 + tid] = f2bf(W[tid * 256 + n]);
        return;
    }
    if (b < 640) {
        const int o = b - 512;
        const int k0 = tid * 2;
        T1[o * 512 + k0]     = f2bf(F1[o * 515 + k0]);
        T1[o * 512 + k0 + 1] = f2bf(F1[o * 515 + k0 + 1]);
        return;
    }
    if (b < 896) {
        const int base = (b - 640) * 960;
        float s = 0.f;
        for (int i = tid; i < 960; i += 256) s += ea[base + i];
        red[tid] = s; __syncthreads();
        for (int off = 128; off > 0; off >>= 1) {
            if (tid < off) red[tid] += red[tid + off];
            __syncthreads();
        }
        if (tid == 0) partial[b - 640] = red[0];
        return;
    }

    // ---- lidar (verified body) ----
    const int lane = tid & 31;
    const int nl   = tid >> 5;
    const int n    = (b - 896) * 8 + nl;

    if (lane < 20) {
        const float v = x[n * 29 + lane];
        sc[nl][lane + 2] = v;
        out[OUT_SCANS + n * 20 + lane] = v;
    } else if (lane < 25) {
        const int pads[5] = {0, 1, 22, 23, 24};
        sc[nl][pads[lane - 20]] = 0.f;
    }
    __syncthreads();

    {
        const int ic = lane & 15;
        const int hi = lane >> 4;
        float w1r[5];
#pragma unroll
        for (int k = 0; k < 5; ++k) w1r[k] = w1[ic * 5 + k];
        const float b1r = b1[ic];
#pragma unroll
        for (int q = 0; q < 5; ++q) {
            const int u  = 2 * q + hi;
            const int p0 = 2 * u;
            float a = b1r, bb = b1r;
#pragma unroll
            for (int k = 0; k < 5; ++k) {
                a  += sc[nl][p0 + k] * w1r[k];
                bb += sc[nl][p0 + 1 + k] * w1r[k];
            }
            pooled[nl][u * 16 + ic] = fmaxf(fmaxf(a, bb), 0.f);
        }
    }
    __syncthreads();

    float macc = 0.f;
    {
        float wreg[48];
#pragma unroll
        for (int i = 0; i < 12; ++i) {
            const float4 v4 = *(const float4*)&w2[lane * 48 + i * 4];
            wreg[i * 4 + 0] = v4.x; wreg[i * 4 + 1] = v4.y;
            wreg[i * 4 + 2] = v4.z; wreg[i * 4 + 3] = v4.w;
        }
        const float b2r = b2[lane];
        float pc[3][16];
#pragma unroll
        for (int i = 0; i < 4; ++i) {
            const float4 v0 = *(const float4*)&pooled[nl][0 * 16 + i * 4];
            const float4 v1 = *(const float4*)&pooled[nl][1 * 16 + i * 4];
            pc[0][i * 4 + 0] = v0.x; pc[0][i * 4 + 1] = v0.y; pc[0][i * 4 + 2] = v0.z; pc[0][i * 4 + 3] = v0.w;
            pc[1][i * 4 + 0] = v1.x; pc[1][i * 4 + 1] = v1.y; pc[1][i * 4 + 2] = v1.z; pc[1][i * 4 + 3] = v1.w;
            pc[2][i * 4 + 0] = 0.f;  pc[2][i * 4 + 1] = 0.f;  pc[2][i * 4 + 2] = 0.f;  pc[2][i * 4 + 3] = 0.f;
        }
#pragma unroll
        for (int t = 0; t < 10; ++t) {
            const int prev = (t + 2) % 3, cur = t % 3, nxt = (t + 1) % 3;
            if (t >= 1) {
                if (t + 1 <= 9) {
#pragma unroll
                    for (int i = 0; i < 4; ++i) {
                        const float4 v4 = *(const float4*)&pooled[nl][(t + 1) * 16 + i * 4];
                        pc[nxt][i * 4 + 0] = v4.x; pc[nxt][i * 4 + 1] = v4.y;
                        pc[nxt][i * 4 + 2] = v4.z; pc[nxt][i * 4 + 3] = v4.w;
                    }
                } else {
#pragma unroll
                    for (int ic = 0; ic < 16; ++ic) pc[nxt][ic] = 0.f;
                }
            }
            float v = b2r;
#pragma unroll
            for (int ic = 0; ic < 16; ++ic) {
                v += pc[prev][ic] * wreg[ic * 3 + 0]
                   + pc[cur][ic]  * wreg[ic * 3 + 1]
                   + pc[nxt][ic]  * wreg[ic * 3 + 2];
            }
            macc += fmaxf(v, 0.f);
        }
    }

    const float feat = macc * 0.1f;
    float z[5];
#pragma unroll
    for (int j = 0; j < 5; ++j) {
        float p = feat * wl[j * 32 + lane];
        p += __shfl_xor(p, 1);
        p += __shfl_xor(p, 2);
        p += __shfl_xor(p, 4);
        p += __shfl_xor(p, 8);
        p += __shfl_xor(p, 16);
        z[j] = fmaxf(bl[j] + p, 0.f);
    }
    float hv = db1[lane];
#pragma unroll
    for (int j = 0; j < 5; ++j) hv += z[j] * dw1[lane * 5 + j];
    hid_lds[nl][lane] = fmaxf(hv, 0.f);
    __syncthreads();

    if (lane < 20) {
        float acc = db2[lane];
#pragma unroll
        for (int k = 0; k < 32; ++k) acc += hid_lds[nl][k] * dw2[lane * 32 + k];
        out[OUT_RECON + n * 20 + lane] = acc;
    }
}

// ============ fused per-graph kernel: GAT1 -> GAT2 -> GAT3 -> heads =========
// Block = one graph (16 nodes), 256 threads (4 waves). h lives in LDS as a
// bf16 row-XOR-swizzled MFMA A-tile (hsb) between layers — no global h.
__global__ __launch_bounds__(256) void graph_kernel(
    const float* __restrict__ x,   const float* __restrict__ ea,
    const float* __restrict__ partial,
    const float* __restrict__ g1_W,
    const float* __restrict__ g1_as, const float* __restrict__ g1_ad,
    const float* __restrict__ g1_We, const float* __restrict__ g1_ae,
    const float* __restrict__ g1_b,
    const unsigned short* __restrict__ WT2,
    const float* __restrict__ g2_as, const float* __restrict__ g2_ad,
    const float* __restrict__ g2_We, const float* __restrict__ g2_ae,
    const float* __restrict__ g2_b,
    const unsigned short* __restrict__ WT3,
    const float* __restrict__ g3_as, const float* __restrict__ g3_ad,
    const float* __restrict__ g3_We, const float* __restrict__ g3_ae,
    const float* __restrict__ g3_b,
    const unsigned short* __restrict__ FT1,
    const float* __restrict__ fc1W, const float* __restrict__ fc1b,
    const float* __restrict__ fc2W, const float* __restrict__ fc2b,
    float* __restrict__ out)
{
    __shared__ char  hsb[8192]   __attribute__((aligned(16)));  // bf16 h tile, swizzled
    __shared__ char  comb2[8192] __attribute__((aligned(16)));  // bf16 gemb tile, swizzled
    __shared__ float xw[16][256];
    __shared__ float coef[16][16][8];      // [s][d][h]
    __shared__ float sals[16][8], sald[16][8];
    __shared__ float sasrc[256], sadst[256], sS[8];
    __shared__ float hs6[16][6];
    __shared__ float lash[8][3];
    __shared__ float hidn[8][128];
    __shared__ float red4[4];
    __shared__ float eamean_s;

    const int tid = threadIdx.x, g = blockIdx.x;
    const int lane = tid & 63, w = tid >> 6;

    // --- edge-attr mean from partials (fixed-order reduction) ---
    {
        float pv = partial[tid];
        pv += __shfl_down(pv, 32);
        pv += __shfl_down(pv, 16);
        pv += __shfl_down(pv, 8);
        pv += __shfl_down(pv, 4);
        pv += __shfl_down(pv, 2);
        pv += __shfl_down(pv, 1);
        if ((tid & 63) == 0) red4[tid >> 6] = pv;
    }
    // --- layer-1 inputs ---
    if (tid < 96) { int i = tid / 6, k = tid % 6; hs6[i][k] = x[(g * 16 + i) * 29 + 20 + k]; }
    if (tid >= 128 && tid < 152) {
        int t = tid - 128, a = t / 3, j = t % 3;
        lash[a][j] = x[(g * 16 + a) * 29 + 26 + j];
    }
    sasrc[tid] = g1_as[tid];
    sadst[tid] = g1_ad[tid];
    if (tid < 8) {
        float s = 0.f;
        for (int c = 0; c < 32; ++c) s += g1_We[tid * 32 + c] * g1_ae[tid * 32 + c];
        sS[tid] = s;
    }
    __syncthreads();
    if (tid == 0) eamean_s = (red4[0] + red4[1] + red4[2] + red4[3]) * (1.f / (float)EDGES);

    // --- layer 1 GEMM (K=6, VALU) ---
    {
        float acc[16];
#pragma unroll
        for (int i = 0; i < 16; ++i) acc[i] = 0.f;
#pragma unroll
        for (int k = 0; k < 6; ++k) {
            float wv = g1_W[k * 256 + tid];
#pragma unroll
            for (int i = 0; i < 16; ++i) acc[i] += hs6[i][k] * wv;
        }
#pragma unroll
        for (int i = 0; i < 16; ++i) xw[i][tid] = acc[i];
    }
    __syncthreads();

    // --- layer 1 attention ---
    if (tid < 128) {
        const int i = tid >> 3, h = tid & 7;
        float s1 = 0.f, s2 = 0.f;
#pragma unroll
        for (int c0 = 0; c0 < 32; c0 += 4) {
            const float4 v  = *(const float4*)&xw[i][h * 32 + c0];
            const float4 a1 = *(const float4*)&sasrc[h * 32 + c0];
            const float4 a2 = *(const float4*)&sadst[h * 32 + c0];
            s1 += v.x * a1.x + v.y * a1.y + v.z * a1.z + v.w * a1.w;
            s2 += v.x * a2.x + v.y * a2.y + v.z * a2.z + v.w * a2.w;
        }
        sals[i][h] = s1;
        sald[i][h] = s2;
    }
    __syncthreads();
    if (tid < 128) {
        const int d = tid >> 3, h = tid & 7;
        const float S = sS[h];
        const float aldv = sald[d][h];
        float alf[16];
        float m = -1e30f;
#pragma unroll
        for (int s = 0; s < 16; ++s) {
            float a;
            if (s == d) a = -1e30f;
            else {
                const int el = s * 15 + d - (d > s ? 1 : 0);
                a = lrelu02(sals[s][h] + aldv + ea[g * EPG + el] * S);
            }
            alf[s] = a;
            m = fmaxf(m, a);
        }
        float sum = 0.f;
#pragma unroll
        for (int s = 0; s < 16; ++s) { alf[s] = expf(alf[s] - m); sum += alf[s]; }
        const float r = 1.f / (sum + 1e-16f);
#pragma unroll
        for (int s = 0; s < 16; ++s) coef[s][d][h] = alf[s] * r;
    }
    __syncthreads();
    // --- layer 1 aggregate -> h1 into hsb (bf16, swizzled) ---
    {
        const int h = tid >> 5;
        const float b = g1_b[tid];
        float o_[16];
#pragma unroll
        for (int d = 0; d < 16; ++d) o_[d] = b;
        for (int s = 0; s < 16; ++s) {
            const float xv = xw[s][tid];
#pragma unroll
            for (int d = 0; d < 16; ++d) o_[d] += coef[s][d][h] * xv;
        }
#pragma unroll
        for (int d = 0; d < 16; ++d) {
            const unsigned short hb = f2bf(fmaxf(o_[d], 0.f));
            *(unsigned short*)(hsb + ((d * 512 + tid * 2) ^ ((d & 7) << 4))) = hb;
        }
    }
    __syncthreads();

    // --- layers 2 and 3 ---
#pragma unroll 1
    for (int ly = 0; ly < 2; ++ly) {
        const unsigned short* WT = ly ? WT3 : WT2;
        const float* as_ = ly ? g3_as : g2_as;
        const float* ad_ = ly ? g3_ad : g2_ad;
        const float* We_ = ly ? g3_We : g2_We;
        const float* ae_ = ly ? g3_ae : g2_ae;
        const float* bi_ = ly ? g3_b  : g2_b;

        sasrc[tid] = as_[tid];
        sadst[tid] = ad_[tid];
        if (tid < 8) {
            float s = 0.f;
            for (int c = 0; c < 32; ++c) s += We_[tid * 32 + c] * ae_[tid * 32 + c];
            sS[tid] = s;
        }
        // MFMA GEMM: xw = h @ W (A from hsb, B from WT)
        {
            f32x4 acc[4];
#pragma unroll
            for (int nt = 0; nt < 4; ++nt) acc[nt] = (f32x4){0.f, 0.f, 0.f, 0.f};
            const int arow = lane & 15;
            const int kg   = lane >> 4;
            const int aswz = (arow & 7) << 4;
            const char* wt = (const char*)WT;
            for (int kk = 0; kk < 8; ++kk) {
                const int ab = arow * 512 + kk * 64 + kg * 8;
                const bf16x4 alo = *(const bf16x4*)(hsb + (ab ^ aswz));
                const bf16x4 ahi = *(const bf16x4*)(hsb + ((ab + 32) ^ aswz));
                const bf16x8 afrag = (bf16x8){alo[0], alo[1], alo[2], alo[3],
                                              ahi[0], ahi[1], ahi[2], ahi[3]};
#pragma unroll
                for (int nt = 0; nt < 4; ++nt) {
                    const int ncol = w * 64 + nt * 16 + arow;
                    const char* bp = wt + ncol * 512 + kk * 64 + kg * 8;
                    const bf16x4 blo = *(const bf16x4*)(bp);
                    const bf16x4 bhi = *(const bf16x4*)(bp + 32);
                    const bf16x8 bfrag = (bf16x8){blo[0], blo[1], blo[2], blo[3],
                                                  bhi[0], bhi[1], bhi[2], bhi[3]};
                    acc[nt] = __builtin_amdgcn_mfma_f32_16x16x32_bf16(afrag, bfrag, acc[nt], 0, 0, 0);
                }
            }
#pragma unroll
            for (int nt = 0; nt < 4; ++nt) {
                const int col = w * 64 + nt * 16 + (lane & 15);
                const int r0  = (lane >> 4) * 4;
#pragma unroll
                for (int r = 0; r < 4; ++r) xw[r0 + r][col] = acc[nt][r];
            }
        }
        __syncthreads();

        if (tid < 128) {
            const int i = tid >> 3, h = tid & 7;
            float s1 = 0.f, s2 = 0.f;
#pragma unroll
            for (int c0 = 0; c0 < 32; c0 += 4) {
                const float4 v  = *(const float4*)&xw[i][h * 32 + c0];
                const float4 a1 = *(const float4*)&sasrc[h * 32 + c0];
                const float4 a2 = *(const float4*)&sadst[h * 32 + c0];
                s1 += v.x * a1.x + v.y * a1.y + v.z * a1.z + v.w * a1.w;
                s2 += v.x * a2.x + v.y * a2.y + v.z * a2.z + v.w * a2.w;
            }
            sals[i][h] = s1;
            sald[i][h] = s2;
        }
        __syncthreads();
        if (tid < 128) {
            const int d = tid >> 3, h = tid & 7;
            const float S = sS[h];
            const float aldv = sald[d][h];
            float alf[16];
            float m = -1e30f;
#pragma unroll
            for (int s = 0; s < 16; ++s) {
                float a;
                if (s == d) a = lrelu02(sals[s][h] + aldv + eamean_s * S);
                else {
                    const int el = s * 15 + d - (d > s ? 1 : 0);
                    a = lrelu02(sals[s][h] + aldv + ea[g * EPG + el] * S);
                }
                alf[s] = a;
                m = fmaxf(m, a);
            }
            float sum = 0.f;
#pragma unroll
            for (int s = 0; s < 16; ++s) { alf[s] = expf(alf[s] - m); sum += alf[s]; }
            const float r = 1.f / (sum + 1e-16f);
#pragma unroll
            for (int s = 0; s < 16; ++s) coef[s][d][h] = alf[s] * r;
        }
        __syncthreads();
        // aggregate -> h into hsb; on last layer also gemb -> comb2
        {
            const int h = tid >> 5;
            const float b = bi_[tid];
            float o_[16];
#pragma unroll
            for (int d = 0; d < 16; ++d) o_[d] = b;
            for (int s = 0; s < 16; ++s) {
                const float xv = xw[s][tid];
#pragma unroll
                for (int d = 0; d < 16; ++d) o_[d] += coef[s][d][h] * xv;
            }
            float gm = 0.f;
#pragma unroll
            for (int d = 0; d < 16; ++d) {
                const float hv = fmaxf(o_[d], 0.f);
                gm += hv;
                *(unsigned short*)(hsb + ((d * 512 + tid * 2) ^ ((d & 7) << 4))) = f2bf(hv);
            }
            if (ly == 1) {
                const unsigned short gb = f2bf(gm * (1.f / 16.f));
#pragma unroll
                for (int r = 0; r < 16; ++r)
                    *(unsigned short*)(comb2 + ((r * 512 + tid * 2) ^ ((r & 7) << 4))) = gb;
            }
        }
        __syncthreads();
    }

    // --- heads fc1 via MFMA: A = [hsb | comb2] (K=512), B = FT1, N=128 ---
    {
        f32x4 acc[2];
        acc[0] = (f32x4){0.f, 0.f, 0.f, 0.f};
        acc[1] = (f32x4){0.f, 0.f, 0.f, 0.f};
        const int arow = lane & 15;
        const int kg   = lane >> 4;
        const int aswz = (arow & 7) << 4;
        for (int kk = 0; kk < 16; ++kk) {
            const char* abase = (kk < 8) ? hsb : comb2;
            const int ab = arow * 512 + (kk & 7) * 64 + kg * 8;
            const bf16x4 alo = *(const bf16x4*)(abase + (ab ^ aswz));
            const bf16x4 ahi = *(const bf16x4*)(abase + ((ab + 32) ^ aswz));
            const bf16x8 afrag = (bf16x8){alo[0], alo[1], alo[2], alo[3],
                                          ahi[0], ahi[1], ahi[2], ahi[3]};
#pragma unroll
            for (int nt = 0; nt < 2; ++nt) {
                const int o = w * 32 + nt * 16 + arow;
                const char* bp = (const char*)FT1 + o * 1024 + kk * 64 + kg * 8;
                const bf16x4 blo = *(const bf16x4*)(bp);
                const bf16x4 bhi = *(const bf16x4*)(bp + 32);
                const bf16x8 bfrag = (bf16x8){blo[0], blo[1], blo[2], blo[3],
                                              bhi[0], bhi[1], bhi[2], bhi[3]};
                acc[nt] = __builtin_amdgcn_mfma_f32_16x16x32_bf16(afrag, bfrag, acc[nt], 0, 0, 0);
            }
        }
#pragma unroll
        for (int nt = 0; nt < 2; ++nt) {
            const int o = w * 32 + nt * 16 + (lane & 15);
            const float wl0 = fc1W[o * 515 + 512];
            const float wl1 = fc1W[o * 515 + 513];
            const float wl2 = fc1W[o * 515 + 514];
            const float b   = fc1b[o];
            const int r0 = (lane >> 4) * 4;
#pragma unroll
            for (int r = 0; r < 4; ++r) {
                const int row = r0 + r;
                if (row < 8) {
                    float v = acc[nt][r] + b
                            + lash[row][0] * wl0 + lash[row][1] * wl1 + lash[row][2] * wl2;
                    hidn[row][o] = fmaxf(v, 0.f);
                }
            }
        }
    }
    __syncthreads();

    // --- fc2 + output transforms (8 agents x 6 outputs) ---
    if (tid < 48) {
        const int a = tid / 6, j = tid % 6;
        const float* wr = &fc2W[j * 128];
        float acc = fc2b[j];
#pragma unroll
        for (int k = 0; k < 128; ++k) acc += wr[k] * hidn[a][k];
        const int base = (g * 8 + a) * 3;
        if (j < 3) {
            const float lim = (j == 2) ? 3.1415927f : 1.0f;
            out[OUT_MEAN + base + j] = tanhf(acc) * lim;
        } else {
            const float sg = 1.f / (1.f + expf(-acc));
            out[OUT_STD + base + (j - 3)] = 0.01f + sg * (0.3f - 0.01f) + 1e-5f;
        }
    }
}

extern "C" void kernel_launch(void* const* d_in, const int* in_sizes, int n_in,
                              void* d_out, int out_size, void* d_ws, size_t ws_size,
                              hipStream_t stream)
{
    const float* x     = (const float*)d_in[0];
    const float* ea    = (const float*)d_in[2];
    const float* lc_w1 = (const float*)d_in[6];
    const float* lc_b1 = (const float*)d_in[7];
    const float* lc_w2 = (const float*)d_in[8];
    const float* lc_b2 = (const float*)d_in[9];
    const float* lc_wl = (const float*)d_in[10];
    const float* lc_bl = (const float*)d_in[11];
    const float* ld_w1 = (const float*)d_in[12];
    const float* ld_b1 = (const float*)d_in[13];
    const float* ld_w2 = (const float*)d_in[14];
    const float* ld_b2 = (const float*)d_in[15];
    const float* g1_W  = (const float*)d_in[16];
    const float* g1_as = (const float*)d_in[17];
    const float* g1_ad = (const float*)d_in[18];
    const float* g1_We = (const float*)d_in[19];
    const float* g1_ae = (const float*)d_in[20];
    const float* g1_b  = (const float*)d_in[21];
    const float* g2_W  = (const float*)d_in[22];
    const float* g2_as = (const float*)d_in[23];
    const float* g2_ad = (const float*)d_in[24];
    const float* g2_We = (const float*)d_in[25];
    const float* g2_ae = (const float*)d_in[26];
    const float* g2_b  = (const float*)d_in[27];
    const float* g3_W  = (const float*)d_in[28];
    const float* g3_as = (const float*)d_in[29];
    const float* g3_ad = (const float*)d_in[30];
    const float* g3_We = (const float*)d_in[31];
    const float* g3_ae = (const float*)d_in[32];
    const float* g3_b  = (const float*)d_in[33];
    const float* fc1_W = (const float*)d_in[34];
    const float* fc1_b = (const float*)d_in[35];
    const float* fc2_W = (const float*)d_in[36];
    const float* fc2_b = (const float*)d_in[37];

    float* out = (float*)d_out;
    unsigned short* WT2 = (unsigned short*)d_ws;        // 128KB
    unsigned short* WT3 = WT2 + 256 * 256;              // 128KB
    unsigned short* FT1 = WT3 + 256 * 256;              // 128KB
    float* partial = (float*)(FT1 + 128 * 512);         // 1KB

    prep_kernel<<<2944, 256, 0, stream>>>(x, ea, g2_W, g3_W, fc1_W,
                                          lc_w1, lc_b1, lc_w2, lc_b2, lc_wl, lc_bl,
                                          ld_w1, ld_b1, ld_w2, ld_b2,
                                          WT2, WT3, FT1, partial, out);

    graph_kernel<<<NGRAPH, 256, 0, stream>>>(x, ea, partial,
                                             g1_W, g1_as, g1_ad, g1_We, g1_ae, g1_b,
                                             WT2, g2_as, g2_ad, g2_We, g2_ae, g2_b,
                                             WT3, g3_as, g3_ad, g3_We, g3_ae, g3_b,
                                             FT1, fc1_W, fc1_b, fc2_W, fc2_b, out);
}